// Round 5
// baseline (355.240 us; speedup 1.0000x reference)
//
#include <hip/hip_runtime.h>

#define BATCH 8
#define GDIM 32
#define NCELL (GDIM * GDIM * GDIM)   // 32768
#define NG (2 * BATCH)               // 16 grids

// ---------------- helpers ----------------
__device__ __forceinline__ void gridParams(const float* bb, float lo[3],
                                           float inv[3], float cs[3]) {
#pragma unroll
    for (int d = 0; d < 3; ++d) {
        lo[d] = bb[d];
        float span = bb[3 + d] - bb[d];
        float iv = (float)GDIM / (span * (1.f + 1e-6f) + 1e-12f);
        inv[d] = iv;
        cs[d] = 1.f / iv;
    }
}

__device__ __forceinline__ int cellOf(float v, float lo, float inv) {
    return min(max((int)floorf((v - lo) * inv), 0), GDIM - 1);
}

__device__ __forceinline__ float axd(float v, float c0, float cw) {
    return fmaxf(fmaxf(c0 - v, v - (c0 + cw)), 0.f);
}

__device__ __forceinline__ void get4pts(const float4& f0, const float4& f1,
                                        const float4& f2, float px[4],
                                        float py[4], float pz[4]) {
    px[0] = f0.x; py[0] = f0.y; pz[0] = f0.z;
    px[1] = f0.w; py[1] = f1.x; pz[1] = f1.y;
    px[2] = f1.z; py[2] = f1.w; pz[2] = f2.x;
    px[3] = f2.y; py[3] = f2.z; pz[3] = f2.w;
}

// ---------------- k1: bbox (blocks 0..NG-1) + zero cnt (rest) ----------------
__global__ __launch_bounds__(256) void k1_bbox_zero(
    const float* __restrict__ ytrue, const float* __restrict__ ypred,
    int N, float* __restrict__ bbox, uint4* __restrict__ cntz)
{
    if (blockIdx.x >= NG) {
        cntz[(blockIdx.x - NG) * 256 + threadIdx.x] = make_uint4(0, 0, 0, 0);
        return;
    }
    int g = blockIdx.x;
    int cloud = g >> 3, b = g & 7;
    const float4* src4 = (const float4*)((cloud ? ypred : ytrue) + (size_t)b * N * 3);
    int nquad = N >> 2;
    float mn[3] = {1e30f, 1e30f, 1e30f}, mx[3] = {-1e30f, -1e30f, -1e30f};
    for (int qk = threadIdx.x; qk < nquad; qk += 256) {
        float4 f0 = src4[3 * qk], f1 = src4[3 * qk + 1], f2 = src4[3 * qk + 2];
        float px[4], py[4], pz[4];
        get4pts(f0, f1, f2, px, py, pz);
#pragma unroll
        for (int k = 0; k < 4; ++k) {
            mn[0] = fminf(mn[0], px[k]); mx[0] = fmaxf(mx[0], px[k]);
            mn[1] = fminf(mn[1], py[k]); mx[1] = fmaxf(mx[1], py[k]);
            mn[2] = fminf(mn[2], pz[k]); mx[2] = fmaxf(mx[2], pz[k]);
        }
    }
#pragma unroll
    for (int o = 32; o; o >>= 1) {
#pragma unroll
        for (int d = 0; d < 3; ++d) {
            mn[d] = fminf(mn[d], __shfl_down(mn[d], o, 64));
            mx[d] = fmaxf(mx[d], __shfl_down(mx[d], o, 64));
        }
    }
    __shared__ float sm[6][4];
    int w = threadIdx.x >> 6, l = threadIdx.x & 63;
    if (l == 0) {
#pragma unroll
        for (int d = 0; d < 3; ++d) { sm[d][w] = mn[d]; sm[3 + d][w] = mx[d]; }
    }
    __syncthreads();
    if (threadIdx.x == 0) {
#pragma unroll
        for (int k = 0; k < 6; ++k) {
            float v = sm[k][0];
#pragma unroll
            for (int i = 1; i < 4; ++i)
                v = (k < 3) ? fminf(v, sm[k][i]) : fmaxf(v, sm[k][i]);
            bbox[g * 6 + k] = v;
        }
    }
}

// ---------------- k2: histogram ----------------
__global__ __launch_bounds__(256) void k2_hist(
    const float* __restrict__ ytrue, const float* __restrict__ ypred,
    int N, const float* __restrict__ bbox, unsigned* __restrict__ cnt)
{
    int nquad = N >> 2;
    int bpg = nquad >> 8;
    int g = blockIdx.x / bpg;
    int qk = (blockIdx.x - g * bpg) * 256 + threadIdx.x;
    int cloud = g >> 3, b = g & 7;
    const float4* src4 = (const float4*)((cloud ? ypred : ytrue) + (size_t)b * N * 3);
    float lo[3], inv[3], cs[3];
    gridParams(bbox + g * 6, lo, inv, cs);
    float4 f0 = src4[3 * qk], f1 = src4[3 * qk + 1], f2 = src4[3 * qk + 2];
    float px[4], py[4], pz[4];
    get4pts(f0, f1, f2, px, py, pz);
    unsigned* Cg = cnt + (size_t)g * NCELL;
#pragma unroll
    for (int k = 0; k < 4; ++k) {
        int cx = cellOf(px[k], lo[0], inv[0]);
        int cy = cellOf(py[k], lo[1], inv[1]);
        int cz = cellOf(pz[k], lo[2], inv[2]);
        atomicAdd(&Cg[(cz * GDIM + cy) * GDIM + cx], 1u);
    }
}

// ---------------- k3: per-grid scan, pack (start<<16)|cnt, zero fill ----------------
__global__ __launch_bounds__(1024) void k3_scan(
    unsigned* __restrict__ cnt, unsigned* __restrict__ sc)
{
    int g = blockIdx.x;
    unsigned* c = cnt + (size_t)g * NCELL;
    unsigned* out = sc + (size_t)g * NCELL;
    int t = threadIdx.x;
    uint4 v[8];
    const uint4* c4 = (const uint4*)(c + t * 32);
    unsigned sum = 0;
#pragma unroll
    for (int j = 0; j < 8; ++j) {
        v[j] = c4[j];
        sum += v[j].x + v[j].y + v[j].z + v[j].w;
    }
    __shared__ unsigned sd[1024];
    sd[t] = sum;
    __syncthreads();
    unsigned val = sum;
    for (int off = 1; off < 1024; off <<= 1) {
        unsigned o = (t >= off) ? sd[t - off] : 0u;
        __syncthreads();
        val += o;
        sd[t] = val;
        __syncthreads();
    }
    unsigned run = val - sum;
    uint4* o4 = (uint4*)(out + t * 32);
    uint4* z4 = (uint4*)(c + t * 32);
#pragma unroll
    for (int j = 0; j < 8; ++j) {
        uint4 w;
        w.x = (run << 16) | v[j].x; run += v[j].x;
        w.y = (run << 16) | v[j].y; run += v[j].y;
        w.z = (run << 16) | v[j].z; run += v[j].z;
        w.w = (run << 16) | v[j].w; run += v[j].w;
        o4[j] = w;
        z4[j] = make_uint4(0, 0, 0, 0);
    }
}

// ---------------- k4: scatter ----------------
__global__ __launch_bounds__(256) void k4_scatter(
    const float* __restrict__ ytrue, const float* __restrict__ ypred,
    int N, const float* __restrict__ bbox, const unsigned* __restrict__ sc,
    unsigned* __restrict__ fill, float4* __restrict__ sorted)
{
    int nquad = N >> 2;
    int bpg = nquad >> 8;
    int g = blockIdx.x / bpg;
    int qk = (blockIdx.x - g * bpg) * 256 + threadIdx.x;
    int cloud = g >> 3, b = g & 7;
    const float4* src4 = (const float4*)((cloud ? ypred : ytrue) + (size_t)b * N * 3);
    float lo[3], inv[3], cs[3];
    gridParams(bbox + g * 6, lo, inv, cs);
    float4 f0 = src4[3 * qk], f1 = src4[3 * qk + 1], f2 = src4[3 * qk + 2];
    float px[4], py[4], pz[4];
    get4pts(f0, f1, f2, px, py, pz);
    const unsigned* Sg = sc + (size_t)g * NCELL;
    unsigned* Fg = fill + (size_t)g * NCELL;
    float4* Og = sorted + (size_t)g * N;
#pragma unroll
    for (int k = 0; k < 4; ++k) {
        int cx = cellOf(px[k], lo[0], inv[0]);
        int cy = cellOf(py[k], lo[1], inv[1]);
        int cz = cellOf(pz[k], lo[2], inv[2]);
        int cid = (cz * GDIM + cy) * GDIM + cx;
        unsigned pos = (Sg[cid] >> 16) + atomicAdd(&Fg[cid], 1u);
        Og[pos] = make_float4(px[k], py[k], pz[k],
                              fmaf(px[k], px[k], fmaf(py[k], py[k], pz[k] * pz[k])));
    }
}

// ---------------- k5: exact NN; one 64-query group per block, 4 waves split rows ----------------
__global__ __launch_bounds__(256) void k5_nn(
    const float4* __restrict__ sorted, const unsigned* __restrict__ sc,
    const float* __restrict__ bbox, int N, double* __restrict__ partial)
{
    __shared__ float4 stage[4][64];
    __shared__ float s_tb[4][64];
    const int wid = threadIdx.x >> 6, lane = threadIdx.x & 63;
    const int ngpg = N >> 6;                 // 128 groups per grid
    int group = blockIdx.x;
    int g = group / ngpg;
    int q0 = (group - g * ngpg) << 6;
    int cloud = g >> 3, b = g & 7;
    int gr = ((1 - cloud) << 3) | b;

    float lo[3], inv[3], cs[3];
    gridParams(bbox + gr * 6, lo, inv, cs);
    const unsigned* __restrict__ C = sc + (size_t)gr * NCELL;
    const float4* __restrict__ P = sorted + (size_t)gr * N;

    // all 4 waves hold the SAME 64 queries (lane-indexed)
    float4 q = sorted[(size_t)g * N + q0 + lane];
    float q2 = q.w;
    float nqx = -2.f * q.x, nqy = -2.f * q.y, nqz = -2.f * q.z;
    float tb = 1e30f;                        // best (d^2 - q2), per-lane partial

    int cx = cellOf(q.x, lo[0], inv[0]);
    int cy = cellOf(q.y, lo[1], inv[1]);
    int cz = cellOf(q.z, lo[2], inv[2]);
    int mnx = cx, mxx = cx, mny = cy, mxy = cy, mnz = cz, mxz = cz;
#pragma unroll
    for (int o = 32; o; o >>= 1) {
        mnx = min(mnx, __shfl_xor(mnx, o, 64)); mxx = max(mxx, __shfl_xor(mxx, o, 64));
        mny = min(mny, __shfl_xor(mny, o, 64)); mxy = max(mxy, __shfl_xor(mxy, o, 64));
        mnz = min(mnz, __shfl_xor(mnz, o, 64)); mxz = max(mxz, __shfl_xor(mxz, o, 64));
    }
    int x0 = __builtin_amdgcn_readfirstlane(max(mnx - 1, 0));
    int x1 = __builtin_amdgcn_readfirstlane(min(mxx + 1, GDIM - 1));
    int y0 = __builtin_amdgcn_readfirstlane(max(mny - 1, 0));
    int y1 = __builtin_amdgcn_readfirstlane(min(mxy + 1, GDIM - 1));
    int z0 = __builtin_amdgcn_readfirstlane(max(mnz - 1, 0));
    int z1 = __builtin_amdgcn_readfirstlane(min(mxz + 1, GDIM - 1));
    int px0 = 0, px1 = -1, py0 = 0, py1 = -1, pz0 = 0, pz1 = -1;

    float4* S = stage[wid];

    auto rangeTest = [&](unsigned a, unsigned bnd, int xa, int xb, float dyz2) {
        if (a >= bnd) return;
        float cw = (float)(xb - xa + 1) * cs[0];
        float dx = axd(q.x, lo[0] + xa * cs[0], cw);
        float lb2 = fmaf(dx, dx, dyz2);
        if (!__any(lb2 * 0.999f < q2 + tb)) return;   // conservative (partial tb)
        for (unsigned cb = a; cb < bnd; cb += 64) {
            unsigned ci = cb + lane;
            if (ci < bnd) S[lane] = P[ci];
            int nk = min(64, (int)(bnd - cb));
            float t0 = 1e30f, t1 = 1e30f;
            int k = 0;
#pragma unroll 4
            for (; k + 2 <= nk; k += 2) {
                float4 pa = S[k], pb = S[k + 1];
                float ta = fmaf(nqx, pa.x, fmaf(nqy, pa.y, fmaf(nqz, pa.z, pa.w)));
                float tc = fmaf(nqx, pb.x, fmaf(nqy, pb.y, fmaf(nqz, pb.z, pb.w)));
                t0 = fminf(t0, ta);
                t1 = fminf(t1, tc);
            }
            if (k < nk) {
                float4 pa = S[k];
                t0 = fminf(t0, fmaf(nqx, pa.x, fmaf(nqy, pa.y, fmaf(nqz, pa.z, pa.w))));
            }
            tb = fminf(tb, fminf(t0, t1));
        }
    };

    for (;;) {   // shell-expansion passes (box state identical in all 4 waves)
        int ny = y1 - y0 + 1;
        int nrows = (z1 - z0 + 1) * ny;
        int zw = z0, yw = y0;
        for (int r0 = 0; r0 < nrows; r0 += 64) {
            int rr = min(r0 + lane, nrows - 1);
            int zq = rr / ny;
            int zi = z0 + zq;
            int yi = y0 + (rr - zq * ny);
            const unsigned* rowp = C + (zi * GDIM + yi) * GDIM;
            unsigned hA = rowp[x0];
            unsigned hB = rowp[x1];
            bool prowL = (zi >= pz0 && zi <= pz1 && yi >= py0 && yi <= py1);
            unsigned hP0 = 0u, hP1 = 0u;
            if (prowL) { hP0 = rowp[px0]; hP1 = rowp[px1]; }
            int rend = min(64, nrows - r0);
            for (int ri = 0; ri < rend; ++ri) {
                if ((ri & 3) == wid) {   // rows round-robin across the 4 waves
                    unsigned ha = (unsigned)__builtin_amdgcn_readlane((int)hA, ri);
                    unsigned hb = (unsigned)__builtin_amdgcn_readlane((int)hB, ri);
                    unsigned rs = ha >> 16;
                    unsigned re = (hb >> 16) + (hb & 0xffffu);
                    if (rs != re) {
                        float dz = axd(q.z, lo[2] + zw * cs[2], cs[2]);
                        float dy = axd(q.y, lo[1] + yw * cs[1], cs[1]);
                        float dyz2 = fmaf(dy, dy, dz * dz);
                        bool pr = (zw >= pz0 && zw <= pz1 && yw >= py0 && yw <= py1);
                        if (pr) {
                            unsigned hp0 = (unsigned)__builtin_amdgcn_readlane((int)hP0, ri);
                            unsigned hp1 = (unsigned)__builtin_amdgcn_readlane((int)hP1, ri);
                            unsigned es = hp0 >> 16;
                            unsigned ee = (hp1 >> 16) + (hp1 & 0xffffu);
                            rangeTest(rs, es, x0, px0 - 1, dyz2);
                            rangeTest(ee, re, px1 + 1, x1, dyz2);
                        } else {
                            rangeTest(rs, re, x0, x1, dyz2);
                        }
                    }
                }
                if (++yw > y1) { yw = y0; ++zw; }
            }
        }
        // combine per-lane tb across the 4 waves (exact min, order-invariant)
        s_tb[wid][lane] = tb;
        __syncthreads();
        tb = fminf(fminf(s_tb[0][lane], s_tb[1][lane]),
                   fminf(s_tb[2][lane], s_tb[3][lane]));
        __syncthreads();   // reads done before next pass overwrites s_tb

        float dbest = q2 + tb;
        float mx = fminf(x0 > 0 ? q.x - (lo[0] + x0 * cs[0]) : 1e30f,
                         x1 < GDIM - 1 ? (lo[0] + (x1 + 1) * cs[0]) - q.x : 1e30f);
        float my = fminf(y0 > 0 ? q.y - (lo[1] + y0 * cs[1]) : 1e30f,
                         y1 < GDIM - 1 ? (lo[1] + (y1 + 1) * cs[1]) - q.y : 1e30f);
        float mz = fminf(z0 > 0 ? q.z - (lo[2] + z0 * cs[2]) : 1e30f,
                         z1 < GDIM - 1 ? (lo[2] + (z1 + 1) * cs[2]) - q.z : 1e30f);
        float m = fminf(mx, fminf(my, mz));
        bool done = (m > 0.f) && (m * m * 0.999f >= dbest);
        bool full = (x0 == 0 && y0 == 0 && z0 == 0 &&
                     x1 == GDIM - 1 && y1 == GDIM - 1 && z1 == GDIM - 1);
        if (full || __all((int)done)) break;   // identical decision in all waves
        px0 = x0; px1 = x1; py0 = y0; py1 = y1; pz0 = z0; pz1 = z1;
        x0 = max(x0 - 1, 0); x1 = min(x1 + 1, GDIM - 1);
        y0 = max(y0 - 1, 0); y1 = min(y1 + 1, GDIM - 1);
        z0 = max(z0 - 1, 0); z1 = min(z1 + 1, GDIM - 1);
    }

    // wave 0 alone owns the output (values identical across waves)
    if (wid == 0) {
        double acc = (double)fmaxf(0.f, q2 + tb);
#pragma unroll
        for (int o = 32; o; o >>= 1) acc += __shfl_down(acc, o, 64);
        if (lane == 0) partial[blockIdx.x] = acc;
    }
}

// ---------------- k6: final reduction ----------------
__global__ __launch_bounds__(256) void k6_final(
    const double* __restrict__ partial, int n, float* __restrict__ out)
{
    double s = 0.0;
    for (int i = threadIdx.x; i < n; i += 256) s += partial[i];
#pragma unroll
    for (int o = 32; o; o >>= 1) s += __shfl_down(s, o, 64);
    __shared__ double sd[4];
    int wid = threadIdx.x >> 6, lane = threadIdx.x & 63;
    if (lane == 0) sd[wid] = s;
    __syncthreads();
    if (threadIdx.x == 0)
        out[0] = (float)((sd[0] + sd[1] + sd[2] + sd[3]) / (double)BATCH);
}

extern "C" void kernel_launch(void* const* d_in, const int* in_sizes, int n_in,
                              void* d_out, int out_size, void* d_ws, size_t ws_size,
                              hipStream_t stream)
{
    const float* ytrue = (const float*)d_in[0];
    const float* ypred = (const float*)d_in[1];
    int N = in_sizes[0] / (BATCH * 3);          // 8192
    size_t total = (size_t)NG * N;              // 131072
    int ngroups = (int)(total >> 6);            // 2048

    char* ws = (char*)d_ws;
    float4*   sorted  = (float4*)ws;   ws += total * sizeof(float4);   // 2 MB
    unsigned* cnt     = (unsigned*)ws; ws += (size_t)NG * NCELL * 4;   // 2 MB (fill)
    unsigned* sc      = (unsigned*)ws; ws += (size_t)NG * NCELL * 4;   // 2 MB
    double*   partial = (double*)ws;   ws += (size_t)ngroups * 8;      // 16 KB
    float*    bbox    = (float*)ws;    ws += NG * 6 * sizeof(float);

    k1_bbox_zero<<<NG + 512, 256, 0, stream>>>(ytrue, ypred, N, bbox, (uint4*)cnt);
    int ptB = (int)(total / 4 / 256);           // 128 blocks
    k2_hist<<<ptB, 256, 0, stream>>>(ytrue, ypred, N, bbox, cnt);
    k3_scan<<<NG, 1024, 0, stream>>>(cnt, sc);
    k4_scatter<<<ptB, 256, 0, stream>>>(ytrue, ypred, N, bbox, sc, cnt, sorted);
    k5_nn<<<ngroups, 256, 0, stream>>>(sorted, sc, bbox, N, partial);
    k6_final<<<1, 256, 0, stream>>>(partial, ngroups, (float*)d_out);
}

// Round 6
// 177.367 us; speedup vs baseline: 2.0029x; 2.0029x over previous
//
#include <hip/hip_runtime.h>

#define BATCH 8
#define GDIM 32
#define NCELL (GDIM * GDIM * GDIM)   // 32768
#define NG (2 * BATCH)               // 16 grids
#define QPW 16                       // queries per wave
#define CAP 192                      // staged candidates per chunk

// ---------------- helpers ----------------
__device__ __forceinline__ void gridParams(const float* bb, float lo[3],
                                           float inv[3], float cs[3]) {
#pragma unroll
    for (int d = 0; d < 3; ++d) {
        lo[d] = bb[d];
        float span = bb[3 + d] - bb[d];
        float iv = (float)GDIM / (span * (1.f + 1e-6f) + 1e-12f);
        inv[d] = iv;
        cs[d] = 1.f / iv;
    }
}

__device__ __forceinline__ int cellOf(float v, float lo, float inv) {
    return min(max((int)floorf((v - lo) * inv), 0), GDIM - 1);
}

__device__ __forceinline__ void get4pts(const float4& f0, const float4& f1,
                                        const float4& f2, float px[4],
                                        float py[4], float pz[4]) {
    px[0] = f0.x; py[0] = f0.y; pz[0] = f0.z;
    px[1] = f0.w; py[1] = f1.x; pz[1] = f1.y;
    px[2] = f1.z; py[2] = f1.w; pz[2] = f2.x;
    px[3] = f2.y; py[3] = f2.z; pz[3] = f2.w;
}

// ---------------- k1: bbox (blocks 0..NG-1) + zero cnt (rest) ----------------
__global__ __launch_bounds__(256) void k1_bbox_zero(
    const float* __restrict__ ytrue, const float* __restrict__ ypred,
    int N, float* __restrict__ bbox, uint4* __restrict__ cntz)
{
    if (blockIdx.x >= NG) {
        cntz[(blockIdx.x - NG) * 256 + threadIdx.x] = make_uint4(0, 0, 0, 0);
        return;
    }
    int g = blockIdx.x;
    int cloud = g >> 3, b = g & 7;
    const float4* src4 = (const float4*)((cloud ? ypred : ytrue) + (size_t)b * N * 3);
    int nquad = N >> 2;
    float mn[3] = {1e30f, 1e30f, 1e30f}, mx[3] = {-1e30f, -1e30f, -1e30f};
    for (int qk = threadIdx.x; qk < nquad; qk += 256) {
        float4 f0 = src4[3 * qk], f1 = src4[3 * qk + 1], f2 = src4[3 * qk + 2];
        float px[4], py[4], pz[4];
        get4pts(f0, f1, f2, px, py, pz);
#pragma unroll
        for (int k = 0; k < 4; ++k) {
            mn[0] = fminf(mn[0], px[k]); mx[0] = fmaxf(mx[0], px[k]);
            mn[1] = fminf(mn[1], py[k]); mx[1] = fmaxf(mx[1], py[k]);
            mn[2] = fminf(mn[2], pz[k]); mx[2] = fmaxf(mx[2], pz[k]);
        }
    }
#pragma unroll
    for (int o = 32; o; o >>= 1) {
#pragma unroll
        for (int d = 0; d < 3; ++d) {
            mn[d] = fminf(mn[d], __shfl_down(mn[d], o, 64));
            mx[d] = fmaxf(mx[d], __shfl_down(mx[d], o, 64));
        }
    }
    __shared__ float sm[6][4];
    int w = threadIdx.x >> 6, l = threadIdx.x & 63;
    if (l == 0) {
#pragma unroll
        for (int d = 0; d < 3; ++d) { sm[d][w] = mn[d]; sm[3 + d][w] = mx[d]; }
    }
    __syncthreads();
    if (threadIdx.x == 0) {
#pragma unroll
        for (int k = 0; k < 6; ++k) {
            float v = sm[k][0];
#pragma unroll
            for (int i = 1; i < 4; ++i)
                v = (k < 3) ? fminf(v, sm[k][i]) : fmaxf(v, sm[k][i]);
            bbox[g * 6 + k] = v;
        }
    }
}

// ---------------- k2: histogram ----------------
__global__ __launch_bounds__(256) void k2_hist(
    const float* __restrict__ ytrue, const float* __restrict__ ypred,
    int N, const float* __restrict__ bbox, unsigned* __restrict__ cnt)
{
    int nquad = N >> 2;
    int bpg = nquad >> 8;
    int g = blockIdx.x / bpg;
    int qk = (blockIdx.x - g * bpg) * 256 + threadIdx.x;
    int cloud = g >> 3, b = g & 7;
    const float4* src4 = (const float4*)((cloud ? ypred : ytrue) + (size_t)b * N * 3);
    float lo[3], inv[3], cs[3];
    gridParams(bbox + g * 6, lo, inv, cs);
    float4 f0 = src4[3 * qk], f1 = src4[3 * qk + 1], f2 = src4[3 * qk + 2];
    float px[4], py[4], pz[4];
    get4pts(f0, f1, f2, px, py, pz);
    unsigned* Cg = cnt + (size_t)g * NCELL;
#pragma unroll
    for (int k = 0; k < 4; ++k) {
        int cx = cellOf(px[k], lo[0], inv[0]);
        int cy = cellOf(py[k], lo[1], inv[1]);
        int cz = cellOf(pz[k], lo[2], inv[2]);
        atomicAdd(&Cg[(cz * GDIM + cy) * GDIM + cx], 1u);
    }
}

// ---------------- k3: per-grid scan, pack (start<<16)|cnt, zero fill ----------------
__global__ __launch_bounds__(1024) void k3_scan(
    unsigned* __restrict__ cnt, unsigned* __restrict__ sc)
{
    int g = blockIdx.x;
    unsigned* c = cnt + (size_t)g * NCELL;
    unsigned* out = sc + (size_t)g * NCELL;
    int t = threadIdx.x;
    uint4 v[8];
    const uint4* c4 = (const uint4*)(c + t * 32);
    unsigned sum = 0;
#pragma unroll
    for (int j = 0; j < 8; ++j) {
        v[j] = c4[j];
        sum += v[j].x + v[j].y + v[j].z + v[j].w;
    }
    __shared__ unsigned sd[1024];
    sd[t] = sum;
    __syncthreads();
    unsigned val = sum;
    for (int off = 1; off < 1024; off <<= 1) {
        unsigned o = (t >= off) ? sd[t - off] : 0u;
        __syncthreads();
        val += o;
        sd[t] = val;
        __syncthreads();
    }
    unsigned run = val - sum;
    uint4* o4 = (uint4*)(out + t * 32);
    uint4* z4 = (uint4*)(c + t * 32);
#pragma unroll
    for (int j = 0; j < 8; ++j) {
        uint4 w;
        w.x = (run << 16) | v[j].x; run += v[j].x;
        w.y = (run << 16) | v[j].y; run += v[j].y;
        w.z = (run << 16) | v[j].z; run += v[j].z;
        w.w = (run << 16) | v[j].w; run += v[j].w;
        o4[j] = w;
        z4[j] = make_uint4(0, 0, 0, 0);
    }
}

// ---------------- k4: scatter ----------------
__global__ __launch_bounds__(256) void k4_scatter(
    const float* __restrict__ ytrue, const float* __restrict__ ypred,
    int N, const float* __restrict__ bbox, const unsigned* __restrict__ sc,
    unsigned* __restrict__ fill, float4* __restrict__ sorted)
{
    int nquad = N >> 2;
    int bpg = nquad >> 8;
    int g = blockIdx.x / bpg;
    int qk = (blockIdx.x - g * bpg) * 256 + threadIdx.x;
    int cloud = g >> 3, b = g & 7;
    const float4* src4 = (const float4*)((cloud ? ypred : ytrue) + (size_t)b * N * 3);
    float lo[3], inv[3], cs[3];
    gridParams(bbox + g * 6, lo, inv, cs);
    float4 f0 = src4[3 * qk], f1 = src4[3 * qk + 1], f2 = src4[3 * qk + 2];
    float px[4], py[4], pz[4];
    get4pts(f0, f1, f2, px, py, pz);
    const unsigned* Sg = sc + (size_t)g * NCELL;
    unsigned* Fg = fill + (size_t)g * NCELL;
    float4* Og = sorted + (size_t)g * N;
#pragma unroll
    for (int k = 0; k < 4; ++k) {
        int cx = cellOf(px[k], lo[0], inv[0]);
        int cy = cellOf(py[k], lo[1], inv[1]);
        int cz = cellOf(pz[k], lo[2], inv[2]);
        int cid = (cz * GDIM + cy) * GDIM + cx;
        unsigned pos = (Sg[cid] >> 16) + atomicAdd(&Fg[cid], 1u);
        Og[pos] = make_float4(px[k], py[k], pz[k],
                              fmaf(px[k], px[k], fmaf(py[k], py[k], pz[k] * pz[k])));
    }
}

// ---------------- k5: exact NN; 16 queries/wave, 4 lanes/query, flat staging ----------------
__global__ __launch_bounds__(256) void k5_nn(
    const float4* __restrict__ sorted, const unsigned* __restrict__ sc,
    const float* __restrict__ bbox, int N, double* __restrict__ partial)
{
    __shared__ float4   S4[4][CAP];
    __shared__ unsigned sPref[4][128];
    __shared__ unsigned sStart[4][128];

    const int wid = threadIdx.x >> 6, lane = threadIdx.x & 63;
    const int slot = lane & 3;
    const int qid = lane >> 2;

    int w = (int)blockIdx.x * 4 + wid;     // 0..8191; block's 4 waves -> 4 grids, same region
    int g = w & 15;
    int qbase = (w >> 4) * QPW;
    int cloud = g >> 3, b = g & 7;
    int gr = ((1 - cloud) << 3) | b;

    float lo[3], inv[3], cs[3];
    gridParams(bbox + gr * 6, lo, inv, cs);
    const unsigned* __restrict__ C = sc + (size_t)gr * NCELL;
    const float4* __restrict__ P = sorted + (size_t)gr * N;

    float4 q = sorted[(size_t)g * N + qbase + qid];
    float q2 = q.w;
    float nqx = -2.f * q.x, nqy = -2.f * q.y, nqz = -2.f * q.z;
    float tb = 1e30f;                 // best (d^2 - q2), partial per lane

    // wave query bbox (for pass>=2 row pruning)
    float qbx0 = q.x, qbx1 = q.x, qby0 = q.y, qby1 = q.y, qbz0 = q.z, qbz1 = q.z;
#pragma unroll
    for (int o = 32; o; o >>= 1) {
        qbx0 = fminf(qbx0, __shfl_xor(qbx0, o, 64));
        qbx1 = fmaxf(qbx1, __shfl_xor(qbx1, o, 64));
        qby0 = fminf(qby0, __shfl_xor(qby0, o, 64));
        qby1 = fmaxf(qby1, __shfl_xor(qby1, o, 64));
        qbz0 = fminf(qbz0, __shfl_xor(qbz0, o, 64));
        qbz1 = fmaxf(qbz1, __shfl_xor(qbz1, o, 64));
    }

    int cx = cellOf(q.x, lo[0], inv[0]);
    int cy = cellOf(q.y, lo[1], inv[1]);
    int cz = cellOf(q.z, lo[2], inv[2]);
    int mnx = cx, mxx = cx, mny = cy, mxy = cy, mnz = cz, mxz = cz;
#pragma unroll
    for (int o = 32; o; o >>= 1) {
        mnx = min(mnx, __shfl_xor(mnx, o, 64)); mxx = max(mxx, __shfl_xor(mxx, o, 64));
        mny = min(mny, __shfl_xor(mny, o, 64)); mxy = max(mxy, __shfl_xor(mxy, o, 64));
        mnz = min(mnz, __shfl_xor(mnz, o, 64)); mxz = max(mxz, __shfl_xor(mxz, o, 64));
    }
    int x0 = __builtin_amdgcn_readfirstlane(max(mnx - 1, 0));
    int x1 = __builtin_amdgcn_readfirstlane(min(mxx + 1, GDIM - 1));
    int y0 = __builtin_amdgcn_readfirstlane(max(mny - 1, 0));
    int y1 = __builtin_amdgcn_readfirstlane(min(mxy + 1, GDIM - 1));
    int z0 = __builtin_amdgcn_readfirstlane(max(mnz - 1, 0));
    int z1 = __builtin_amdgcn_readfirstlane(min(mxz + 1, GDIM - 1));
    int px0 = 0, px1 = -1, py0 = 0, py1 = -1, pz0 = 0, pz1 = -1;

    float4*   St = S4[wid];
    unsigned* Pf = sPref[wid];
    unsigned* Ss = sStart[wid];
    float dmax = 1e30f;               // wave-max current best d^2 (inf -> no prune)

    for (;;) {   // shell-expansion passes (box state wave-uniform)
        int nyr = y1 - y0 + 1;
        int nrows = (z1 - z0 + 1) * nyr;
        for (int r0 = 0; r0 < nrows; r0 += 64) {
            int rr = r0 + lane;
            bool rv = rr < nrows;
            int rrc = rv ? rr : 0;
            int zq = rrc / nyr;
            int zi = z0 + zq;
            int yi = y0 + (rrc - zq * nyr);
            unsigned e0s = 0, e0l = 0, e1s = 0, e1l = 0;
            if (rv) {
                bool skip = false;
                if (dmax < 1e29f) {   // conservative row prune vs wave query-bbox
                    float ry0 = lo[1] + yi * cs[1];
                    float rz0 = lo[2] + zi * cs[2];
                    float bx0 = lo[0] + x0 * cs[0];
                    float bx1 = lo[0] + (x1 + 1) * cs[0];
                    float dx = fmaxf(fmaxf(bx0 - qbx1, qbx0 - bx1), 0.f);
                    float dy = fmaxf(fmaxf(ry0 - qby1, qby0 - (ry0 + cs[1])), 0.f);
                    float dz = fmaxf(fmaxf(rz0 - qbz1, qbz0 - (rz0 + cs[2])), 0.f);
                    float lb2 = fmaf(dx, dx, fmaf(dy, dy, dz * dz));
                    skip = (lb2 * 0.999f >= dmax);
                }
                if (!skip) {
                    const unsigned* rowp = C + (zi * GDIM + yi) * GDIM;
                    unsigned hA = rowp[x0];
                    unsigned hB = rowp[x1];
                    unsigned rs = hA >> 16;
                    unsigned re = (hB >> 16) + (hB & 0xffffu);
                    bool pr = (zi >= pz0 && zi <= pz1 && yi >= py0 && yi <= py1);
                    if (pr) {
                        unsigned hP0 = rowp[px0];
                        unsigned hP1 = rowp[px1];
                        unsigned es = hP0 >> 16;
                        unsigned ee = (hP1 >> 16) + (hP1 & 0xffffu);
                        e0s = rs; e0l = es - rs;
                        e1s = ee; e1l = re - ee;
                    } else {
                        e0s = rs; e0l = re - rs;
                    }
                }
            }
            // wave scan of lengths -> prefix table
            unsigned mylen = e0l + e1l;
            unsigned incl = mylen;
#pragma unroll
            for (int o = 1; o < 64; o <<= 1) {
                unsigned u = __shfl_up(incl, o, 64);
                if (lane >= o) incl += u;
            }
            unsigned excl = incl - mylen;
            Pf[2 * lane] = excl;
            Pf[2 * lane + 1] = excl + e0l;
            Ss[2 * lane] = e0s;
            Ss[2 * lane + 1] = e1s;
            unsigned T = __shfl(incl, 63, 64);
            if (T == 0) continue;
            asm volatile("s_waitcnt lgkmcnt(0)" ::: "memory");

            for (unsigned base = 0; base < T; base += CAP) {
                unsigned chunk = min((unsigned)CAP, T - base);
                for (unsigned t = lane; t < chunk; t += 64) {
                    unsigned tt = base + t;
                    int r = 0;
#pragma unroll
                    for (int st = 64; st; st >>= 1) {
                        int m = r + st;
                        if (m < 128 && Pf[m] <= tt) r = m;
                    }
                    St[t] = P[Ss[r] + (tt - Pf[r])];
                }
                asm volatile("s_waitcnt lgkmcnt(0)" ::: "memory");
                float t0 = 1e30f, t1 = 1e30f;
                unsigned j = slot;
#pragma unroll 4
                for (; j + 4 < chunk; j += 8) {
                    float4 pa = St[j], pb = St[j + 4];
                    float ta = fmaf(nqx, pa.x, fmaf(nqy, pa.y, fmaf(nqz, pa.z, pa.w)));
                    float tc = fmaf(nqx, pb.x, fmaf(nqy, pb.y, fmaf(nqz, pb.z, pb.w)));
                    t0 = fminf(t0, ta);
                    t1 = fminf(t1, tc);
                }
                if (j < chunk) {
                    float4 pa = St[j];
                    t0 = fminf(t0, fmaf(nqx, pa.x, fmaf(nqy, pa.y, fmaf(nqz, pa.z, pa.w))));
                }
                tb = fminf(tb, fminf(t0, t1));
                asm volatile("" ::: "memory");   // keep staging of next chunk after reads
            }
        }

        // combine per-query (4 slots)
        float tq = fminf(tb, __shfl_xor(tb, 1, 64));
        tq = fminf(tq, __shfl_xor(tq, 2, 64));
        tb = tq;
        float d2q = q2 + tq;
        float dm = d2q;
#pragma unroll
        for (int o = 32; o; o >>= 1) dm = fmaxf(dm, __shfl_xor(dm, o, 64));
        dmax = dm;

        bool full = (x0 == 0 && y0 == 0 && z0 == 0 &&
                     x1 == GDIM - 1 && y1 == GDIM - 1 && z1 == GDIM - 1);
        float mx = fminf(x0 > 0 ? q.x - (lo[0] + x0 * cs[0]) : 1e30f,
                         x1 < GDIM - 1 ? (lo[0] + (x1 + 1) * cs[0]) - q.x : 1e30f);
        float my = fminf(y0 > 0 ? q.y - (lo[1] + y0 * cs[1]) : 1e30f,
                         y1 < GDIM - 1 ? (lo[1] + (y1 + 1) * cs[1]) - q.y : 1e30f);
        float mz = fminf(z0 > 0 ? q.z - (lo[2] + z0 * cs[2]) : 1e30f,
                         z1 < GDIM - 1 ? (lo[2] + (z1 + 1) * cs[2]) - q.z : 1e30f);
        float m = fminf(mx, fminf(my, mz));
        bool done = (m > 0.f) && (m * m * 0.999f >= d2q);
        if (full || __all((int)done)) break;
        px0 = x0; px1 = x1; py0 = y0; py1 = y1; pz0 = z0; pz1 = z1;
        x0 = max(x0 - 1, 0); x1 = min(x1 + 1, GDIM - 1);
        y0 = max(y0 - 1, 0); y1 = min(y1 + 1, GDIM - 1);
        z0 = max(z0 - 1, 0); z1 = min(z1 + 1, GDIM - 1);
    }

    double acc = (slot == 0) ? (double)fmaxf(0.f, q2 + tb) : 0.0;
#pragma unroll
    for (int o = 32; o; o >>= 1) acc += __shfl_down(acc, o, 64);
    if (lane == 0) partial[w] = acc;
}

// ---------------- k6: final reduction ----------------
__global__ __launch_bounds__(256) void k6_final(
    const double* __restrict__ partial, int n, float* __restrict__ out)
{
    double s = 0.0;
    for (int i = threadIdx.x; i < n; i += 256) s += partial[i];
#pragma unroll
    for (int o = 32; o; o >>= 1) s += __shfl_down(s, o, 64);
    __shared__ double sd[4];
    int wid = threadIdx.x >> 6, lane = threadIdx.x & 63;
    if (lane == 0) sd[wid] = s;
    __syncthreads();
    if (threadIdx.x == 0)
        out[0] = (float)((sd[0] + sd[1] + sd[2] + sd[3]) / (double)BATCH);
}

extern "C" void kernel_launch(void* const* d_in, const int* in_sizes, int n_in,
                              void* d_out, int out_size, void* d_ws, size_t ws_size,
                              hipStream_t stream)
{
    const float* ytrue = (const float*)d_in[0];
    const float* ypred = (const float*)d_in[1];
    int N = in_sizes[0] / (BATCH * 3);          // 8192
    size_t total = (size_t)NG * N;              // 131072
    int nwaves = (int)(total / QPW);            // 8192

    char* ws = (char*)d_ws;
    float4*   sorted  = (float4*)ws;   ws += total * sizeof(float4);   // 2 MB
    unsigned* cnt     = (unsigned*)ws; ws += (size_t)NG * NCELL * 4;   // 2 MB (fill)
    unsigned* sc      = (unsigned*)ws; ws += (size_t)NG * NCELL * 4;   // 2 MB
    double*   partial = (double*)ws;   ws += (size_t)nwaves * 8;       // 64 KB
    float*    bbox    = (float*)ws;    ws += NG * 6 * sizeof(float);

    k1_bbox_zero<<<NG + 512, 256, 0, stream>>>(ytrue, ypred, N, bbox, (uint4*)cnt);
    int ptB = (int)(total / 4 / 256);           // 128 blocks
    k2_hist<<<ptB, 256, 0, stream>>>(ytrue, ypred, N, bbox, cnt);
    k3_scan<<<NG, 1024, 0, stream>>>(cnt, sc);
    k4_scatter<<<ptB, 256, 0, stream>>>(ytrue, ypred, N, bbox, sc, cnt, sorted);
    k5_nn<<<nwaves / 4, 256, 0, stream>>>(sorted, sc, bbox, N, partial);
    k6_final<<<1, 256, 0, stream>>>(partial, nwaves, (float*)d_out);
}